// Round 1
// baseline (1749.508 us; speedup 1.0000x reference)
//
#include <hip/hip_runtime.h>
#include <hip/hip_bf16.h>
#include <cstdint>
#include <cstddef>

#define TILE_BM 64
#define TILE_BN 64
#define TILE_BK 32

// ---------------------------------------------------------------------------
// Encoder: out[r][c] = sum_k X[r][k]*W[c][k] + bias[c] + emb[ids[r]][c]
// M x K  @  (64 x K)^T  -> M x 64.   Block = 256 thr, tile 64x64, 4x4/thread.
// ---------------------------------------------------------------------------
__global__ __launch_bounds__(256)
void encoder_kernel(const float* __restrict__ X, int K,
                    const float* __restrict__ W,
                    const float* __restrict__ bias,
                    const int* __restrict__ ids,
                    const float* __restrict__ emb,
                    float* __restrict__ out, int M)
{
    __shared__ float As[TILE_BK][TILE_BM + 4];
    __shared__ float Bs[TILE_BK][TILE_BN + 4];
    const int tid  = threadIdx.x;
    const int row0 = blockIdx.x * TILE_BM;
    const int tr   = tid >> 4;   // 0..15 -> rows tr*4..tr*4+3
    const int tc   = tid & 15;   // 0..15 -> cols tc*4..tc*4+3

    float acc[4][4];
#pragma unroll
    for (int i = 0; i < 4; i++)
#pragma unroll
        for (int j = 0; j < 4; j++) acc[i][j] = 0.f;

    for (int k0 = 0; k0 < K; k0 += TILE_BK) {
        // A tile: 64 rows x 32 k  (512 float4, 2 per thread)
#pragma unroll
        for (int i = 0; i < 2; i++) {
            int idx = tid + i * 256;
            int r = idx >> 3;
            int j = idx & 7;
            int gr = row0 + r;
            float4 v = make_float4(0.f, 0.f, 0.f, 0.f);
            if (gr < M) v = *(const float4*)&X[(size_t)gr * K + k0 + j * 4];
            As[j * 4 + 0][r] = v.x; As[j * 4 + 1][r] = v.y;
            As[j * 4 + 2][r] = v.z; As[j * 4 + 3][r] = v.w;
        }
        // B tile: 64 out-channels x 32 k
#pragma unroll
        for (int i = 0; i < 2; i++) {
            int idx = tid + i * 256;
            int c = idx >> 3;
            int j = idx & 7;
            float4 v = *(const float4*)&W[(size_t)c * K + k0 + j * 4];
            Bs[j * 4 + 0][c] = v.x; Bs[j * 4 + 1][c] = v.y;
            Bs[j * 4 + 2][c] = v.z; Bs[j * 4 + 3][c] = v.w;
        }
        __syncthreads();
#pragma unroll
        for (int kk = 0; kk < TILE_BK; kk++) {
            float4 av = *(const float4*)&As[kk][tr * 4];
            float4 bv = *(const float4*)&Bs[kk][tc * 4];
            float a_[4] = {av.x, av.y, av.z, av.w};
            float b_[4] = {bv.x, bv.y, bv.z, bv.w};
#pragma unroll
            for (int i = 0; i < 4; i++)
#pragma unroll
                for (int j = 0; j < 4; j++) acc[i][j] += a_[i] * b_[j];
        }
        __syncthreads();
    }

    float4 bv = *(const float4*)&bias[tc * 4];
#pragma unroll
    for (int i = 0; i < 4; i++) {
        int r = row0 + tr * 4 + i;
        if (r >= M) continue;
        int id = ids[r];
        float4 ev = *(const float4*)&emb[(size_t)id * 64 + tc * 4];
        float4 o;
        o.x = acc[i][0] + bv.x + ev.x;
        o.y = acc[i][1] + bv.y + ev.y;
        o.z = acc[i][2] + bv.z + ev.z;
        o.w = acc[i][3] + bv.w + ev.w;
        *(float4*)&out[(size_t)r * 64 + tc * 4] = o;
    }
}

// ---------------------------------------------------------------------------
// SAGE linear: out = A0 @ W0^T + A1 @ W1^T + bias  (optional ReLU)
// A0,A1: M x 64.  W0,W1: 64 x 64.
// ---------------------------------------------------------------------------
__global__ __launch_bounds__(256)
void sage_linear_kernel(const float* __restrict__ A0, const float* __restrict__ W0,
                        const float* __restrict__ A1, const float* __restrict__ W1,
                        const float* __restrict__ bias, float* __restrict__ out,
                        int M, int relu)
{
    __shared__ float As[TILE_BK][TILE_BM + 4];
    __shared__ float Bs[TILE_BK][TILE_BN + 4];
    const int tid  = threadIdx.x;
    const int row0 = blockIdx.x * TILE_BM;
    const int tr   = tid >> 4;
    const int tc   = tid & 15;

    float acc[4][4];
#pragma unroll
    for (int i = 0; i < 4; i++)
#pragma unroll
        for (int j = 0; j < 4; j++) acc[i][j] = 0.f;

    for (int phase = 0; phase < 2; phase++) {
        const float* A = phase ? A1 : A0;
        const float* W = phase ? W1 : W0;
        for (int k0 = 0; k0 < 64; k0 += TILE_BK) {
#pragma unroll
            for (int i = 0; i < 2; i++) {
                int idx = tid + i * 256;
                int r = idx >> 3;
                int j = idx & 7;
                int gr = row0 + r;
                float4 v = make_float4(0.f, 0.f, 0.f, 0.f);
                if (gr < M) v = *(const float4*)&A[(size_t)gr * 64 + k0 + j * 4];
                As[j * 4 + 0][r] = v.x; As[j * 4 + 1][r] = v.y;
                As[j * 4 + 2][r] = v.z; As[j * 4 + 3][r] = v.w;
            }
#pragma unroll
            for (int i = 0; i < 2; i++) {
                int idx = tid + i * 256;
                int c = idx >> 3;
                int j = idx & 7;
                float4 v = *(const float4*)&W[(size_t)c * 64 + k0 + j * 4];
                Bs[j * 4 + 0][c] = v.x; Bs[j * 4 + 1][c] = v.y;
                Bs[j * 4 + 2][c] = v.z; Bs[j * 4 + 3][c] = v.w;
            }
            __syncthreads();
#pragma unroll
            for (int kk = 0; kk < TILE_BK; kk++) {
                float4 av = *(const float4*)&As[kk][tr * 4];
                float4 bv = *(const float4*)&Bs[kk][tc * 4];
                float a_[4] = {av.x, av.y, av.z, av.w};
                float b_[4] = {bv.x, bv.y, bv.z, bv.w};
#pragma unroll
                for (int i = 0; i < 4; i++)
#pragma unroll
                    for (int j = 0; j < 4; j++) acc[i][j] += a_[i] * b_[j];
            }
            __syncthreads();
        }
    }

    float4 bv = *(const float4*)&bias[tc * 4];
#pragma unroll
    for (int i = 0; i < 4; i++) {
        int r = row0 + tr * 4 + i;
        if (r >= M) continue;
        float4 o;
        o.x = acc[i][0] + bv.x;
        o.y = acc[i][1] + bv.y;
        o.z = acc[i][2] + bv.z;
        o.w = acc[i][3] + bv.w;
        if (relu) {
            o.x = fmaxf(o.x, 0.f); o.y = fmaxf(o.y, 0.f);
            o.z = fmaxf(o.z, 0.f); o.w = fmaxf(o.w, 0.f);
        }
        *(float4*)&out[(size_t)r * 64 + tc * 4] = o;
    }
}

// ---------------------------------------------------------------------------
// Degree count + reciprocal
// ---------------------------------------------------------------------------
__global__ void deg_kernel(const int* __restrict__ src, const int* __restrict__ dst,
                           float* __restrict__ deg_t, float* __restrict__ deg_m, int E)
{
    int e = blockIdx.x * 256 + threadIdx.x;
    if (e < E) {
        atomicAdd(&deg_t[src[e]], 1.f);
        atomicAdd(&deg_m[dst[e]], 1.f);
    }
}

__global__ void inv_kernel(float* __restrict__ d, int n)
{
    int i = blockIdx.x * 256 + threadIdx.x;
    if (i < n) d[i] = 1.f / fmaxf(d[i], 1.f);
}

// ---------------------------------------------------------------------------
// Row gather: out[r] = src[ids[r]]   (rows of 64 floats, 16 lanes/row)
// ---------------------------------------------------------------------------
__global__ void gather_rows_kernel(const float* __restrict__ src, const int* __restrict__ ids,
                                   float* __restrict__ out, int M)
{
    int gid = blockIdx.x * 256 + threadIdx.x;
    int r = gid >> 4;
    int j = gid & 15;
    if (r < M) {
        *(float4*)&out[(size_t)r * 64 + j * 4] =
            *(const float4*)&src[(size_t)ids[r] * 64 + j * 4];
    }
}

// ---------------------------------------------------------------------------
// Edge scatter (mean folded in): agg[to[e]][c] += feat[from[e]][c] * inv_deg[to[e]]
// 64 lanes per edge (one channel each).
// ---------------------------------------------------------------------------
__global__ __launch_bounds__(256)
void scatter_kernel(const float* __restrict__ feat, const int* __restrict__ idx_from,
                    const int* __restrict__ idx_to, const float* __restrict__ inv_deg,
                    float* __restrict__ agg, int E)
{
    int gid = blockIdx.x * 256 + threadIdx.x;
    int e = gid >> 6;
    int c = gid & 63;
    if (e < E) {
        int f = idx_from[e];
        int t = idx_to[e];
        float v = feat[(size_t)f * 64 + c] * inv_deg[t];
        atomicAdd(&agg[(size_t)t * 64 + c], v);
    }
}

// ---------------------------------------------------------------------------
// Classifier: out[g] = dot(xt[es[g]], xm[ed[g]])   (16 lanes/edge, float4)
// ---------------------------------------------------------------------------
__global__ __launch_bounds__(256)
void classify_kernel(const float* __restrict__ xt, const float* __restrict__ xm,
                     const int* __restrict__ es, const int* __restrict__ ed,
                     float* __restrict__ out, int EL)
{
    int gid = blockIdx.x * 256 + threadIdx.x;
    int g = gid >> 4;
    int j = gid & 15;
    if (g < EL) {
        int s = es[g];
        int d = ed[g];
        float4 a = *(const float4*)&xt[(size_t)s * 64 + j * 4];
        float4 b = *(const float4*)&xm[(size_t)d * 64 + j * 4];
        float v = a.x * b.x + a.y * b.y + a.z * b.z + a.w * b.w;
        v += __shfl_down(v, 8, 16);
        v += __shfl_down(v, 4, 16);
        v += __shfl_down(v, 2, 16);
        v += __shfl_down(v, 1, 16);
        if (j == 0) out[g] = v;
    }
}

// ---------------------------------------------------------------------------
extern "C" void kernel_launch(void* const* d_in, const int* in_sizes, int n_in,
                              void* d_out, int out_size, void* d_ws, size_t ws_size,
                              hipStream_t stream)
{
    const float* x_thesis  = (const float*)d_in[0];
    const int*   thesis_id = (const int*)d_in[1];
    const int*   mentor_id = (const int*)d_in[2];
    const int*   edge_src  = (const int*)d_in[3];
    const int*   edge_dst  = (const int*)d_in[4];
    const int*   el_src    = (const int*)d_in[5];
    const int*   el_dst    = (const int*)d_in[6];
    const float* lin_W     = (const float*)d_in[7];
    const float* lin_b     = (const float*)d_in[8];
    const float* emb_t     = (const float*)d_in[9];
    const float* emb_m     = (const float*)d_in[10];
    const float* Wl_tm0    = (const float*)d_in[11];
    const float* Wr_tm0    = (const float*)d_in[12];
    const float* b_tm0     = (const float*)d_in[13];
    const float* Wl_mt0    = (const float*)d_in[14];
    const float* Wr_mt0    = (const float*)d_in[15];
    const float* b_mt0     = (const float*)d_in[16];
    const float* Wl_tm1    = (const float*)d_in[17];
    const float* Wr_tm1    = (const float*)d_in[18];
    const float* b_tm1     = (const float*)d_in[19];
    const float* Wl_mt1    = (const float*)d_in[20];
    const float* Wr_mt1    = (const float*)d_in[21];
    const float* b_mt1     = (const float*)d_in[22];

    const int NT = in_sizes[1];
    const int NM = in_sizes[2];
    const int E  = in_sizes[3];
    const int EL = in_sizes[5];
    const int FT = in_sizes[0] / NT;

    // workspace layout (256B aligned)
    char* ws = (char*)d_ws;
    size_t off = 0;
    auto alloc = [&](size_t bytes) -> void* {
        void* p = ws + off;
        off += (bytes + 255) & ~(size_t)255;
        return p;
    };
    float* xt_a  = (float*)alloc((size_t)NT * 64 * 4);
    float* xt_b  = (float*)alloc((size_t)NT * 64 * 4);
    float* agg_t = (float*)alloc((size_t)NT * 64 * 4);
    float* xm_a  = (float*)alloc((size_t)NM * 64 * 4);
    float* xm_b  = (float*)alloc((size_t)NM * 64 * 4);
    float* agg_m = (float*)alloc((size_t)NM * 64 * 4);
    float* deg_t = (float*)alloc((size_t)NT * 4);
    float* deg_m = (float*)alloc((size_t)NM * 4);
    (void)ws_size; (void)n_in; (void)out_size;

    // degrees (shared by both layers); deg -> 1/max(deg,1) in place
    hipMemsetAsync(deg_t, 0, (size_t)NT * 4, stream);
    hipMemsetAsync(deg_m, 0, (size_t)NM * 4, stream);
    deg_kernel<<<(E + 255) / 256, 256, 0, stream>>>(edge_src, edge_dst, deg_t, deg_m, E);
    inv_kernel<<<(NT + 255) / 256, 256, 0, stream>>>(deg_t, NT);
    inv_kernel<<<(NM + 255) / 256, 256, 0, stream>>>(deg_m, NM);

    // node encoders
    encoder_kernel<<<(NT + 63) / 64, 256, 0, stream>>>(x_thesis, FT, lin_W, lin_b,
                                                       thesis_id, emb_t, xt_a, NT);
    gather_rows_kernel<<<(NM * 16 + 255) / 256, 256, 0, stream>>>(emb_m, mentor_id, xm_a, NM);

    const int scatter_grid = (int)(((size_t)E * 64 + 255) / 256);

    // ---- layer 0 (ReLU) ----
    hipMemsetAsync(agg_m, 0, (size_t)NM * 64 * 4, stream);
    hipMemsetAsync(agg_t, 0, (size_t)NT * 64 * 4, stream);
    scatter_kernel<<<scatter_grid, 256, 0, stream>>>(xt_a, edge_src, edge_dst, deg_m, agg_m, E);
    scatter_kernel<<<scatter_grid, 256, 0, stream>>>(xm_a, edge_dst, edge_src, deg_t, agg_t, E);
    sage_linear_kernel<<<(NM + 63) / 64, 256, 0, stream>>>(agg_m, Wl_tm0, xm_a, Wr_tm0,
                                                           b_tm0, xm_b, NM, 1);
    sage_linear_kernel<<<(NT + 63) / 64, 256, 0, stream>>>(agg_t, Wl_mt0, xt_a, Wr_mt0,
                                                           b_mt0, xt_b, NT, 1);

    // ---- layer 1 (no ReLU) ----
    hipMemsetAsync(agg_m, 0, (size_t)NM * 64 * 4, stream);
    hipMemsetAsync(agg_t, 0, (size_t)NT * 64 * 4, stream);
    scatter_kernel<<<scatter_grid, 256, 0, stream>>>(xt_b, edge_src, edge_dst, deg_m, agg_m, E);
    scatter_kernel<<<scatter_grid, 256, 0, stream>>>(xm_b, edge_dst, edge_src, deg_t, agg_t, E);
    sage_linear_kernel<<<(NM + 63) / 64, 256, 0, stream>>>(agg_m, Wl_tm1, xm_b, Wr_tm1,
                                                           b_tm1, xm_a, NM, 0);
    sage_linear_kernel<<<(NT + 63) / 64, 256, 0, stream>>>(agg_t, Wl_mt1, xt_b, Wr_mt1,
                                                           b_mt1, xt_a, NT, 0);

    // ---- edge classifier ----
    classify_kernel<<<(int)(((size_t)EL * 16 + 255) / 256), 256, 0, stream>>>(
        xt_a, xm_a, el_src, el_dst, (float*)d_out, EL);
}